// Round 3
// baseline (1205.343 us; speedup 1.0000x reference)
//
#include <hip/hip_runtime.h>
#include <hip/hip_bf16.h>
#include <cstdint>

// SpatialAttention: B=8, C=256, CO=128, H=W=64, N=4096
//   q = Wq@p + bq   [B,N,CO]   (proj2: f32 VALU, X read once, s_load W)
//   k = Wk@b + bk   [B,N,CO]   (+ fused Vb = bf16(b))
//   e = q k^T       [B,N,N]    split-bf16 3-pass, 32x32x16 MFMA, XCD swizzle
//   attn = softmax(e, -1)      (output 1; also writes bf16 copy to ws)
//   out = attn @ b^T [B,C,N]   (output 0; pv3: 256cx64n, LDS 2-phase, 32x32)
//
// d_ws layout (318,767,104 B): attnb bf16[8*4096*4096], qhi/qlo/khi/klo
// 4x bf16[8*4096*128], Vb bf16[8*256*4096].

#define BATCH 8
#define CCH   256
#define COO   128
#define NPIX  4096

typedef __bf16 bf16x8 __attribute__((ext_vector_type(8)));
typedef __bf16 bf16x4 __attribute__((ext_vector_type(4)));
typedef float  f32x4  __attribute__((ext_vector_type(4)));
typedef float  f32x16 __attribute__((ext_vector_type(16)));

__device__ __forceinline__ void gload16(const void* g, void* l) {
  __builtin_amdgcn_global_load_lds(
      (const __attribute__((address_space(1))) uint32_t*)g,
      (__attribute__((address_space(3))) uint32_t*)l, 16, 0, 0);
}

// ---------------- K1: projection. Thread-per-pixel, acc[64], wave-uniform W
// (s_load), X read exactly once. Optional fused bf16 cast of X into Vb.
__global__ __launch_bounds__(256) void proj2_kernel(
    const float* __restrict__ X,    // [B][C][N]
    const float* __restrict__ W,    // [CO][C]
    const float* __restrict__ bias, // [CO]
    __bf16* __restrict__ out_hi,    // [B][N][CO]
    __bf16* __restrict__ out_lo,
    __bf16* __restrict__ Vb)        // [B][C][N] or nullptr
{
  const int b   = blockIdx.y;
  const int n0  = blockIdx.x * 128;
  const int tid = threadIdx.x;
  const int w = tid >> 6, l = tid & 63;
  const int o0 = (w >> 1) * 64;          // wave-uniform -> scalar W loads
  const int n  = n0 + (w & 1) * 64 + l;
  const bool wV = (Vb != nullptr) && ((w >> 1) == 0);

  const float* Xc = X + (size_t)b * CCH * NPIX + n;
  const float* Wb = W + (size_t)o0 * CCH;

  float acc[64];
#pragma unroll
  for (int o = 0; o < 64; ++o) acc[o] = 0.f;

  for (int c4 = 0; c4 < CCH; c4 += 4) {
    const float x0 = Xc[(size_t)(c4 + 0) * NPIX];
    const float x1 = Xc[(size_t)(c4 + 1) * NPIX];
    const float x2 = Xc[(size_t)(c4 + 2) * NPIX];
    const float x3 = Xc[(size_t)(c4 + 3) * NPIX];
    if (wV) {
      Vb[((size_t)b * CCH + c4 + 0) * NPIX + n] = (__bf16)x0;
      Vb[((size_t)b * CCH + c4 + 1) * NPIX + n] = (__bf16)x1;
      Vb[((size_t)b * CCH + c4 + 2) * NPIX + n] = (__bf16)x2;
      Vb[((size_t)b * CCH + c4 + 3) * NPIX + n] = (__bf16)x3;
    }
#pragma unroll
    for (int o = 0; o < 64; ++o) {
      const float4 wv = *reinterpret_cast<const float4*>(Wb + (size_t)o * CCH + c4);
      acc[o] = fmaf(wv.x, x0, acc[o]);
      acc[o] = fmaf(wv.y, x1, acc[o]);
      acc[o] = fmaf(wv.z, x2, acc[o]);
      acc[o] = fmaf(wv.w, x3, acc[o]);
    }
  }

  const size_t obase = ((size_t)b * NPIX + n) * COO + o0;
#pragma unroll
  for (int g = 0; g < 8; ++g) {
    bf16x8 hv, lv;
#pragma unroll
    for (int j = 0; j < 8; ++j) {
      const float v = acc[g * 8 + j] + bias[o0 + g * 8 + j];
      const __bf16 h = (__bf16)v;
      hv[j] = h;
      lv[j] = (__bf16)(v - (float)h);
    }
    *reinterpret_cast<bf16x8*>(out_hi + obase + g * 8) = hv;
    *reinterpret_cast<bf16x8*>(out_lo + obase + g * 8) = lv;
  }
}

// ---------------- K2: energy, 32x32x16 MFMA, split-bf16 3-pass, XCD swizzle.
// 128x128 tile per WG; wave tile 64x64 = 2x2 frags of 32x32.
__global__ __launch_bounds__(256) void energy2_kernel(
    const __bf16* __restrict__ qhip, const __bf16* __restrict__ qlop,
    const __bf16* __restrict__ khip, const __bf16* __restrict__ klop,
    float* __restrict__ eout)
{
  // bijective XCD chunk swizzle: 8192 blocks, each XCD gets one full batch
  const int lin = blockIdx.x;
  const int s   = (lin & 7) * 1024 + (lin >> 3);
  const int b   = s >> 10;
  const int r   = s & 1023;
  const int n0  = (r >> 5) << 7;
  const int m0  = (r & 31) << 7;

  const int tid = threadIdx.x;
  const int w = tid >> 6, l = tid & 63;
  const int wr = w >> 1, wc = w & 1;
  const int rl = l & 31;
  const int k8 = (l >> 5) * 8;

  const size_t qb = ((size_t)b * NPIX + n0 + wr * 64 + rl) * COO + k8;
  const size_t kb = ((size_t)b * NPIX + m0 + wc * 64 + rl) * COO + k8;

  f32x16 acc[2][2];
#pragma unroll
  for (int fr = 0; fr < 2; ++fr)
#pragma unroll
    for (int fc = 0; fc < 2; ++fc)
#pragma unroll
      for (int r2 = 0; r2 < 16; ++r2) acc[fr][fc][r2] = 0.f;

#pragma unroll
  for (int kc = 0; kc < 8; ++kc) {
    const int ko = kc * 16;
    bf16x8 ah[2], al[2], bh[2], bl[2];
#pragma unroll
    for (int f = 0; f < 2; ++f) {
      ah[f] = *reinterpret_cast<const bf16x8*>(qhip + qb + (size_t)f * 32 * COO + ko);
      al[f] = *reinterpret_cast<const bf16x8*>(qlop + qb + (size_t)f * 32 * COO + ko);
      bh[f] = *reinterpret_cast<const bf16x8*>(khip + kb + (size_t)f * 32 * COO + ko);
      bl[f] = *reinterpret_cast<const bf16x8*>(klop + kb + (size_t)f * 32 * COO + ko);
    }
#pragma unroll
    for (int fr = 0; fr < 2; ++fr)
#pragma unroll
      for (int fc = 0; fc < 2; ++fc) {
        acc[fr][fc] = __builtin_amdgcn_mfma_f32_32x32x16_bf16(ah[fr], bh[fc], acc[fr][fc], 0, 0, 0);
        acc[fr][fc] = __builtin_amdgcn_mfma_f32_32x32x16_bf16(ah[fr], bl[fc], acc[fr][fc], 0, 0, 0);
        acc[fr][fc] = __builtin_amdgcn_mfma_f32_32x32x16_bf16(al[fr], bh[fc], acc[fr][fc], 0, 0, 0);
      }
  }

  const int hi4 = (l >> 5) * 4;
#pragma unroll
  for (int fr = 0; fr < 2; ++fr)
#pragma unroll
    for (int fc = 0; fc < 2; ++fc)
#pragma unroll
      for (int r2 = 0; r2 < 16; ++r2) {
        const int row = n0 + wr * 64 + fr * 32 + (r2 & 3) + 8 * (r2 >> 2) + hi4;
        const int col = m0 + wc * 64 + fc * 32 + rl;
        eout[((size_t)b * NPIX + row) * NPIX + col] = acc[fr][fc][r2];
      }
}

// ---------------- K3: row softmax in place; optional bf16 copy to ws
template <bool WRITE_BF16>
__global__ __launch_bounds__(256) void softmax_kernel(
    float* __restrict__ attn, __bf16* __restrict__ attnb)
{
  const size_t row = blockIdx.x;
  float* p = attn + row * NPIX;
  const int tid = threadIdx.x;
  const int w = tid >> 6, l = tid & 63;

  float4 v[4];
#pragma unroll
  for (int j = 0; j < 4; ++j)
    v[j] = *reinterpret_cast<const float4*>(p + j * 1024 + tid * 4);

  float m = -1e30f;
#pragma unroll
  for (int j = 0; j < 4; ++j)
    m = fmaxf(m, fmaxf(fmaxf(v[j].x, v[j].y), fmaxf(v[j].z, v[j].w)));
#pragma unroll
  for (int off = 32; off; off >>= 1) m = fmaxf(m, __shfl_xor(m, off));

  __shared__ float smax[4];
  __shared__ float ssum[4];
  if (l == 0) smax[w] = m;
  __syncthreads();
  m = fmaxf(fmaxf(smax[0], smax[1]), fmaxf(smax[2], smax[3]));

  float s = 0.f;
#pragma unroll
  for (int j = 0; j < 4; ++j) {
    v[j].x = __expf(v[j].x - m); s += v[j].x;
    v[j].y = __expf(v[j].y - m); s += v[j].y;
    v[j].z = __expf(v[j].z - m); s += v[j].z;
    v[j].w = __expf(v[j].w - m); s += v[j].w;
  }
#pragma unroll
  for (int off = 32; off; off >>= 1) s += __shfl_xor(s, off);
  if (l == 0) ssum[w] = s;
  __syncthreads();
  s = ssum[0] + ssum[1] + ssum[2] + ssum[3];
  const float inv = 1.0f / s;

#pragma unroll
  for (int j = 0; j < 4; ++j) {
    v[j].x *= inv; v[j].y *= inv; v[j].z *= inv; v[j].w *= inv;
    *reinterpret_cast<float4*>(p + j * 1024 + tid * 4) = v[j];
    if (WRITE_BF16) {
      bf16x4 t;
      t[0] = (__bf16)v[j].x; t[1] = (__bf16)v[j].y;
      t[2] = (__bf16)v[j].z; t[3] = (__bf16)v[j].w;
      *reinterpret_cast<bf16x4*>(attnb + row * NPIX + j * 1024 + tid * 4) = t;
    }
  }
}

// ---------------- K4: pv3 — 256c x 64n per WG, attn read once, 32x32x16,
// gload_lds 2-phase with XOR-swizzled LDS (T2/rule#21). LDS 80KB -> 2 WG/CU.
__global__ __launch_bounds__(256) void pv3_kernel(
    const __bf16* __restrict__ V,   // [B][C][M] bf16
    const __bf16* __restrict__ An,  // [B][N][M] bf16 (softmaxed)
    float* __restrict__ out)        // [B][C][N]
{
  __shared__ uint8_t ldsb[2 * 40960];
  const int lin = blockIdx.x;                 // 512 blocks
  const int s   = (lin & 7) * 64 + (lin >> 3);
  const int n0  = (s & 63) * 64;
  const int b   = s >> 6;
  const int tid = threadIdx.x;
  const int w = tid >> 6, l = tid & 63;
  const int rl = l & 31;

  const uint8_t* Vbase = (const uint8_t*)(V + (size_t)b * CCH * NPIX);
  const uint8_t* Abase = (const uint8_t*)(An + ((size_t)b * NPIX + n0) * NPIX);

  f32x16 acc[2][2];
#pragma unroll
  for (int fr = 0; fr < 2; ++fr)
#pragma unroll
    for (int fc = 0; fc < 2; ++fc)
#pragma unroll
      for (int r2 = 0; r2 < 16; ++r2) acc[fr][fc][r2] = 0.f;

  // stage V(256x64, 32KB) + A(64x64, 8KB) for m-chunk t into buffer buf.
  // LDS dest linear; source column pre-XOR'd so reads use col ^ ((row&7)<<4).
#define STAGE(buf, t)                                                         \
  {                                                                           \
    const int tb = (t) * 128;                                                 \
    _Pragma("unroll")                                                         \
    for (int q = 0; q < 8; ++q) {                                             \
      const int dst = q * 4096 + tid * 16;                                    \
      const int row = dst >> 7, colb = dst & 127;                             \
      gload16(Vbase + (size_t)row * 8192 + tb + (colb ^ ((row & 7) << 4)),    \
              ldsb + (buf) * 40960 + dst);                                    \
    }                                                                         \
    _Pragma("unroll")                                                         \
    for (int q = 0; q < 2; ++q) {                                             \
      const int dst = q * 4096 + tid * 16;                                    \
      const int row = dst >> 7, colb = dst & 127;                             \
      gload16(Abase + (size_t)row * 8192 + tb + (colb ^ ((row & 7) << 4)),    \
              ldsb + (buf) * 40960 + 32768 + dst);                            \
    }                                                                         \
  }

  STAGE(0, 0);
  __syncthreads();

  for (int t = 0; t < 64; ++t) {
    const int cur = t & 1;
    if (t + 1 < 64) STAGE(cur ^ 1, t + 1);
    const uint8_t* Vt = ldsb + cur * 40960;
    const uint8_t* At = Vt + 32768;
#pragma unroll
    for (int kc = 0; kc < 4; ++kc) {
      const int colb = kc * 32 + ((l >> 5) << 4);
      bf16x8 a[2], bb[2];
#pragma unroll
      for (int f = 0; f < 2; ++f) {
        const int row = w * 64 + f * 32 + rl;
        a[f] = *reinterpret_cast<const bf16x8*>(
            Vt + row * 128 + (colb ^ ((row & 7) << 4)));
      }
#pragma unroll
      for (int f = 0; f < 2; ++f) {
        const int row = f * 32 + rl;
        bb[f] = *reinterpret_cast<const bf16x8*>(
            At + row * 128 + (colb ^ ((row & 7) << 4)));
      }
#pragma unroll
      for (int fr = 0; fr < 2; ++fr)
#pragma unroll
        for (int fc = 0; fc < 2; ++fc)
          acc[fr][fc] = __builtin_amdgcn_mfma_f32_32x32x16_bf16(a[fr], bb[fc], acc[fr][fc], 0, 0, 0);
    }
    __syncthreads();
  }
#undef STAGE

  const int hi4 = (l >> 5) * 4;
#pragma unroll
  for (int fr = 0; fr < 2; ++fr)
#pragma unroll
    for (int fc = 0; fc < 2; ++fc)
#pragma unroll
      for (int r2 = 0; r2 < 16; ++r2) {
        const int c = w * 64 + fr * 32 + (r2 & 3) + 8 * (r2 >> 2) + hi4;
        const int n = n0 + fc * 32 + rl;
        out[((size_t)b * CCH + c) * NPIX + n] = acc[fr][fc][r2];
      }
}

// ---------------- K4 (fallback): direct f32-attn pv (round-1 proven)
__global__ __launch_bounds__(256) void pv_kernel(
    const __bf16* __restrict__ V,    // [B][C][M] bf16
    const float*  __restrict__ attn, // [B][N][M] f32
    float* __restrict__ out)         // [B][C][N]
{
  const int b   = blockIdx.z;
  const int n0  = blockIdx.x * 64;
  const int tid = threadIdx.x;
  const int w = tid >> 6, l = tid & 63;
  const int wr = w >> 1, wc = w & 1;
  const int rl = l & 15, k8 = (l >> 4) * 8;

  const __bf16* vp = V + ((size_t)b * CCH + wr * 128 + rl) * NPIX + k8;
  const float*  ap = attn + ((size_t)b * NPIX + n0 + wc * 32 + rl) * NPIX + k8;

  f32x4 zero = {0.f, 0.f, 0.f, 0.f};
  f32x4 acc[8][2];
#pragma unroll
  for (int fr = 0; fr < 8; ++fr) { acc[fr][0] = zero; acc[fr][1] = zero; }

  for (int ks = 0; ks < 128; ++ks) {
    const int mo = ks * 32;
    bf16x8 a[8];
#pragma unroll
    for (int f = 0; f < 8; ++f)
      a[f] = *reinterpret_cast<const bf16x8*>(vp + (size_t)f * 16 * NPIX + mo);
    bf16x8 bb[2];
#pragma unroll
    for (int f = 0; f < 2; ++f) {
      const float* aq = ap + (size_t)f * 16 * NPIX + mo;
      float4 x = *reinterpret_cast<const float4*>(aq);
      float4 y = *reinterpret_cast<const float4*>(aq + 4);
      bf16x8 t;
      t[0] = (__bf16)x.x; t[1] = (__bf16)x.y; t[2] = (__bf16)x.z; t[3] = (__bf16)x.w;
      t[4] = (__bf16)y.x; t[5] = (__bf16)y.y; t[6] = (__bf16)y.z; t[7] = (__bf16)y.w;
      bb[f] = t;
    }
#pragma unroll
    for (int fr = 0; fr < 8; ++fr) {
      acc[fr][0] = __builtin_amdgcn_mfma_f32_16x16x32_bf16(a[fr], bb[0], acc[fr][0], 0, 0, 0);
      acc[fr][1] = __builtin_amdgcn_mfma_f32_16x16x32_bf16(a[fr], bb[1], acc[fr][1], 0, 0, 0);
    }
  }

  const int cg = (l >> 4) * 4;
#pragma unroll
  for (int fr = 0; fr < 8; ++fr)
#pragma unroll
    for (int fc = 0; fc < 2; ++fc)
#pragma unroll
      for (int r = 0; r < 4; ++r) {
        const int c = wr * 128 + fr * 16 + cg + r;
        const int n = n0 + wc * 32 + fc * 16 + rl;
        out[((size_t)b * CCH + c) * NPIX + n] = acc[fr][fc][r];
      }
}

extern "C" void kernel_launch(void* const* d_in, const int* in_sizes, int n_in,
                              void* d_out, int out_size, void* d_ws, size_t ws_size,
                              hipStream_t stream)
{
  const float* p  = (const float*)d_in[0];
  const float* bi = (const float*)d_in[1];
  const float* Wq = (const float*)d_in[2];
  const float* bq = (const float*)d_in[3];
  const float* Wk = (const float*)d_in[4];
  const float* bk = (const float*)d_in[5];

  float* out  = (float*)d_out;                       // [8][256][4096]
  float* attn = out + (size_t)BATCH * CCH * NPIX;    // [8][4096][4096]

  const size_t QK  = (size_t)BATCH * NPIX * COO;     // 4,194,304 elems
  const size_t VB  = (size_t)BATCH * CCH * NPIX;     // 8,388,608 elems
  const size_t ANB = (size_t)BATCH * NPIX * NPIX;    // 134,217,728 elems
  const size_t need_bf16 = (ANB + 4 * QK + VB) * 2;  // 318,767,104 B

  if (ws_size >= need_bf16) {
    __bf16* attnb = (__bf16*)d_ws;
    __bf16* qhi = attnb + ANB;
    __bf16* qlo = qhi + QK;
    __bf16* khi = qlo + QK;
    __bf16* klo = khi + QK;
    __bf16* Vb  = klo + QK;

    proj2_kernel<<<dim3(32, 8), 256, 0, stream>>>(p,  Wq, bq, qhi, qlo, nullptr);
    proj2_kernel<<<dim3(32, 8), 256, 0, stream>>>(bi, Wk, bk, khi, klo, Vb);
    energy2_kernel<<<8192, 256, 0, stream>>>(qhi, qlo, khi, klo, attn);
    softmax_kernel<true><<<32768, 256, 0, stream>>>(attn, attnb);
    pv3_kernel<<<512, 256, 0, stream>>>(Vb, attnb, out);
  } else {
    __bf16* qhi = (__bf16*)d_ws;
    __bf16* qlo = qhi + QK;
    __bf16* khi = qlo + QK;
    __bf16* klo = khi + QK;
    __bf16* Vb  = klo + QK;

    proj2_kernel<<<dim3(32, 8), 256, 0, stream>>>(p,  Wq, bq, qhi, qlo, nullptr);
    proj2_kernel<<<dim3(32, 8), 256, 0, stream>>>(bi, Wk, bk, khi, klo, Vb);
    energy2_kernel<<<8192, 256, 0, stream>>>(qhi, qlo, khi, klo, attn);
    softmax_kernel<false><<<32768, 256, 0, stream>>>(attn, nullptr);
    pv_kernel<<<dim3(64, 1, 8), 256, 0, stream>>>(Vb, attn, out);
  }
}

// Round 4
// 788.837 us; speedup vs baseline: 1.5280x; 1.5280x over previous
//
#include <hip/hip_runtime.h>
#include <hip/hip_bf16.h>
#include <cstdint>

// SpatialAttention: B=8, C=256, CO=128, H=W=64, N=4096
//   q = Wq@p + bq   [B,N,CO]   (proj3: W in LDS, 1px/thread, X L3-resident)
//   k = Wk@b + bk   [B,N,CO]   (+ fused Vb = bf16(b) on o-tile-0 blocks)
//   e = q k^T       [B,N,N]    split-bf16 3-pass, 32x32x16 MFMA, XCD swizzle
//   attn = softmax(e, -1)      (output 1; also writes bf16 copy to ws)
//   out = attn @ b^T [B,C,N]   (output 0; pv3: 256cx64n, LDS 2-phase, 32x32)
//
// d_ws layout (318,767,104 B): attnb bf16[8*4096*4096], qhi/qlo/khi/klo
// 4x bf16[8*4096*128], Vb bf16[8*256*4096].

#define BATCH 8
#define CCH   256
#define COO   128
#define NPIX  4096

typedef __bf16 bf16x8 __attribute__((ext_vector_type(8)));
typedef __bf16 bf16x4 __attribute__((ext_vector_type(4)));
typedef float  f32x4  __attribute__((ext_vector_type(4)));
typedef float  f32x16 __attribute__((ext_vector_type(16)));

__device__ __forceinline__ void gload16(const void* g, void* l) {
  __builtin_amdgcn_global_load_lds(
      (const __attribute__((address_space(1))) uint32_t*)g,
      (__attribute__((address_space(3))) uint32_t*)l, 16, 0, 0);
}

// ---------------- K1: proj3 — W tile (32 o-rows) in LDS, 1 pixel/thread.
// grid (16, 4, 8); X re-read 4x but X (32MB) is L3-resident.
__global__ __launch_bounds__(256) void proj3_kernel(
    const float* __restrict__ X,    // [B][C][N]
    const float* __restrict__ W,    // [CO][C]
    const float* __restrict__ bias, // [CO]
    __bf16* __restrict__ out_hi,    // [B][N][CO]
    __bf16* __restrict__ out_lo,
    __bf16* __restrict__ Vb)        // [B][C][N] or nullptr
{
  __shared__ float wlds[32][256];
  __shared__ float blds[32];
  const int b   = blockIdx.z;
  const int o0  = blockIdx.y * 32;
  const int tid = threadIdx.x;
  const int n   = blockIdx.x * 256 + tid;

  for (int i = tid; i < 2048; i += 256) {     // 32 rows x 64 quads
    const int r = i >> 6, q = (i & 63) * 4;
    *reinterpret_cast<float4*>(&wlds[r][q]) =
        *reinterpret_cast<const float4*>(W + (size_t)(o0 + r) * CCH + q);
  }
  if (tid < 32) blds[tid] = bias[o0 + tid];
  __syncthreads();

  const float* Xc = X + (size_t)b * CCH * NPIX + n;
  const bool wV = (Vb != nullptr) && (blockIdx.y == 0);

  float acc[32];
#pragma unroll
  for (int o = 0; o < 32; ++o) acc[o] = 0.f;

  for (int c4 = 0; c4 < CCH; c4 += 4) {
    const float x0 = Xc[(size_t)(c4 + 0) * NPIX];
    const float x1 = Xc[(size_t)(c4 + 1) * NPIX];
    const float x2 = Xc[(size_t)(c4 + 2) * NPIX];
    const float x3 = Xc[(size_t)(c4 + 3) * NPIX];
    if (wV) {
      Vb[((size_t)b * CCH + c4 + 0) * NPIX + n] = (__bf16)x0;
      Vb[((size_t)b * CCH + c4 + 1) * NPIX + n] = (__bf16)x1;
      Vb[((size_t)b * CCH + c4 + 2) * NPIX + n] = (__bf16)x2;
      Vb[((size_t)b * CCH + c4 + 3) * NPIX + n] = (__bf16)x3;
    }
#pragma unroll
    for (int o = 0; o < 32; ++o) {
      const float4 wv = *reinterpret_cast<const float4*>(&wlds[o][c4]);
      acc[o] = fmaf(wv.x, x0, acc[o]);
      acc[o] = fmaf(wv.y, x1, acc[o]);
      acc[o] = fmaf(wv.z, x2, acc[o]);
      acc[o] = fmaf(wv.w, x3, acc[o]);
    }
  }

  const size_t obase = ((size_t)b * NPIX + n) * COO + o0;
#pragma unroll
  for (int g = 0; g < 4; ++g) {
    bf16x8 hv, lv;
#pragma unroll
    for (int j = 0; j < 8; ++j) {
      const float v = acc[g * 8 + j] + blds[g * 8 + j];
      const __bf16 h = (__bf16)v;
      hv[j] = h;
      lv[j] = (__bf16)(v - (float)h);
    }
    *reinterpret_cast<bf16x8*>(out_hi + obase + g * 8) = hv;
    *reinterpret_cast<bf16x8*>(out_lo + obase + g * 8) = lv;
  }
}

// ---------------- K2: energy, 32x32x16 MFMA, split-bf16 3-pass, XCD swizzle.
__global__ __launch_bounds__(256) void energy2_kernel(
    const __bf16* __restrict__ qhip, const __bf16* __restrict__ qlop,
    const __bf16* __restrict__ khip, const __bf16* __restrict__ klop,
    float* __restrict__ eout)
{
  const int lin = blockIdx.x;
  const int s   = (lin & 7) * 1024 + (lin >> 3);
  const int b   = s >> 10;
  const int r   = s & 1023;
  const int n0  = (r >> 5) << 7;
  const int m0  = (r & 31) << 7;

  const int tid = threadIdx.x;
  const int w = tid >> 6, l = tid & 63;
  const int wr = w >> 1, wc = w & 1;
  const int rl = l & 31;
  const int k8 = (l >> 5) * 8;

  const size_t qb = ((size_t)b * NPIX + n0 + wr * 64 + rl) * COO + k8;
  const size_t kb = ((size_t)b * NPIX + m0 + wc * 64 + rl) * COO + k8;

  f32x16 acc[2][2];
#pragma unroll
  for (int fr = 0; fr < 2; ++fr)
#pragma unroll
    for (int fc = 0; fc < 2; ++fc)
#pragma unroll
      for (int r2 = 0; r2 < 16; ++r2) acc[fr][fc][r2] = 0.f;

#pragma unroll
  for (int kc = 0; kc < 8; ++kc) {
    const int ko = kc * 16;
    bf16x8 ah[2], al[2], bh[2], bl[2];
#pragma unroll
    for (int f = 0; f < 2; ++f) {
      ah[f] = *reinterpret_cast<const bf16x8*>(qhip + qb + (size_t)f * 32 * COO + ko);
      al[f] = *reinterpret_cast<const bf16x8*>(qlop + qb + (size_t)f * 32 * COO + ko);
      bh[f] = *reinterpret_cast<const bf16x8*>(khip + kb + (size_t)f * 32 * COO + ko);
      bl[f] = *reinterpret_cast<const bf16x8*>(klop + kb + (size_t)f * 32 * COO + ko);
    }
#pragma unroll
    for (int fr = 0; fr < 2; ++fr)
#pragma unroll
      for (int fc = 0; fc < 2; ++fc) {
        acc[fr][fc] = __builtin_amdgcn_mfma_f32_32x32x16_bf16(ah[fr], bh[fc], acc[fr][fc], 0, 0, 0);
        acc[fr][fc] = __builtin_amdgcn_mfma_f32_32x32x16_bf16(ah[fr], bl[fc], acc[fr][fc], 0, 0, 0);
        acc[fr][fc] = __builtin_amdgcn_mfma_f32_32x32x16_bf16(al[fr], bh[fc], acc[fr][fc], 0, 0, 0);
      }
  }

  const int hi4 = (l >> 5) * 4;
#pragma unroll
  for (int fr = 0; fr < 2; ++fr)
#pragma unroll
    for (int fc = 0; fc < 2; ++fc)
#pragma unroll
      for (int r2 = 0; r2 < 16; ++r2) {
        const int row = n0 + wr * 64 + fr * 32 + (r2 & 3) + 8 * (r2 >> 2) + hi4;
        const int col = m0 + wc * 64 + fc * 32 + rl;
        eout[((size_t)b * NPIX + row) * NPIX + col] = acc[fr][fc][r2];
      }
}

// ---------------- K3: row softmax in place; optional bf16 copy to ws
template <bool WRITE_BF16>
__global__ __launch_bounds__(256) void softmax_kernel(
    float* __restrict__ attn, __bf16* __restrict__ attnb)
{
  const size_t row = blockIdx.x;
  float* p = attn + row * NPIX;
  const int tid = threadIdx.x;
  const int w = tid >> 6, l = tid & 63;

  float4 v[4];
#pragma unroll
  for (int j = 0; j < 4; ++j)
    v[j] = *reinterpret_cast<const float4*>(p + j * 1024 + tid * 4);

  float m = -1e30f;
#pragma unroll
  for (int j = 0; j < 4; ++j)
    m = fmaxf(m, fmaxf(fmaxf(v[j].x, v[j].y), fmaxf(v[j].z, v[j].w)));
#pragma unroll
  for (int off = 32; off; off >>= 1) m = fmaxf(m, __shfl_xor(m, off));

  __shared__ float smax[4];
  __shared__ float ssum[4];
  if (l == 0) smax[w] = m;
  __syncthreads();
  m = fmaxf(fmaxf(smax[0], smax[1]), fmaxf(smax[2], smax[3]));

  float s = 0.f;
#pragma unroll
  for (int j = 0; j < 4; ++j) {
    v[j].x = __expf(v[j].x - m); s += v[j].x;
    v[j].y = __expf(v[j].y - m); s += v[j].y;
    v[j].z = __expf(v[j].z - m); s += v[j].z;
    v[j].w = __expf(v[j].w - m); s += v[j].w;
  }
#pragma unroll
  for (int off = 32; off; off >>= 1) s += __shfl_xor(s, off);
  if (l == 0) ssum[w] = s;
  __syncthreads();
  s = ssum[0] + ssum[1] + ssum[2] + ssum[3];
  const float inv = 1.0f / s;

#pragma unroll
  for (int j = 0; j < 4; ++j) {
    v[j].x *= inv; v[j].y *= inv; v[j].z *= inv; v[j].w *= inv;
    *reinterpret_cast<float4*>(p + j * 1024 + tid * 4) = v[j];
    if (WRITE_BF16) {
      bf16x4 t;
      t[0] = (__bf16)v[j].x; t[1] = (__bf16)v[j].y;
      t[2] = (__bf16)v[j].z; t[3] = (__bf16)v[j].w;
      *reinterpret_cast<bf16x4*>(attnb + row * NPIX + j * 1024 + tid * 4) = t;
    }
  }
}

// ---------------- K4: pv3 — 256c x 64n per WG, attn read once, 32x32x16,
// gload_lds 2-phase with XOR-swizzled LDS. LDS 80KB -> 2 WG/CU.
__global__ __launch_bounds__(256) void pv3_kernel(
    const __bf16* __restrict__ V,   // [B][C][M] bf16
    const __bf16* __restrict__ An,  // [B][N][M] bf16 (softmaxed)
    float* __restrict__ out)        // [B][C][N]
{
  __shared__ uint8_t ldsb[2 * 40960];
  const int lin = blockIdx.x;                 // 512 blocks
  const int s   = (lin & 7) * 64 + (lin >> 3);
  const int n0  = (s & 63) * 64;
  const int b   = s >> 6;
  const int tid = threadIdx.x;
  const int w = tid >> 6, l = tid & 63;
  const int rl = l & 31;

  const uint8_t* Vbase = (const uint8_t*)(V + (size_t)b * CCH * NPIX);
  const uint8_t* Abase = (const uint8_t*)(An + ((size_t)b * NPIX + n0) * NPIX);

  f32x16 acc[2][2];
#pragma unroll
  for (int fr = 0; fr < 2; ++fr)
#pragma unroll
    for (int fc = 0; fc < 2; ++fc)
#pragma unroll
      for (int r2 = 0; r2 < 16; ++r2) acc[fr][fc][r2] = 0.f;

#define STAGE(buf, t)                                                         \
  {                                                                           \
    const int tb = (t) * 128;                                                 \
    _Pragma("unroll")                                                         \
    for (int q = 0; q < 8; ++q) {                                             \
      const int dst = q * 4096 + tid * 16;                                    \
      const int row = dst >> 7, colb = dst & 127;                             \
      gload16(Vbase + (size_t)row * 8192 + tb + (colb ^ ((row & 7) << 4)),    \
              ldsb + (buf) * 40960 + dst);                                    \
    }                                                                         \
    _Pragma("unroll")                                                         \
    for (int q = 0; q < 2; ++q) {                                             \
      const int dst = q * 4096 + tid * 16;                                    \
      const int row = dst >> 7, colb = dst & 127;                             \
      gload16(Abase + (size_t)row * 8192 + tb + (colb ^ ((row & 7) << 4)),    \
              ldsb + (buf) * 40960 + 32768 + dst);                            \
    }                                                                         \
  }

  STAGE(0, 0);
  __syncthreads();

  for (int t = 0; t < 64; ++t) {
    const int cur = t & 1;
    if (t + 1 < 64) STAGE(cur ^ 1, t + 1);
    const uint8_t* Vt = ldsb + cur * 40960;
    const uint8_t* At = Vt + 32768;
#pragma unroll
    for (int kc = 0; kc < 4; ++kc) {
      const int colb = kc * 32 + ((l >> 5) << 4);
      bf16x8 a[2], bb[2];
#pragma unroll
      for (int f = 0; f < 2; ++f) {
        const int row = w * 64 + f * 32 + rl;
        a[f] = *reinterpret_cast<const bf16x8*>(
            Vt + row * 128 + (colb ^ ((row & 7) << 4)));
      }
#pragma unroll
      for (int f = 0; f < 2; ++f) {
        const int row = f * 32 + rl;
        bb[f] = *reinterpret_cast<const bf16x8*>(
            At + row * 128 + (colb ^ ((row & 7) << 4)));
      }
#pragma unroll
      for (int fr = 0; fr < 2; ++fr)
#pragma unroll
        for (int fc = 0; fc < 2; ++fc)
          acc[fr][fc] = __builtin_amdgcn_mfma_f32_32x32x16_bf16(a[fr], bb[fc], acc[fr][fc], 0, 0, 0);
    }
    __syncthreads();
  }
#undef STAGE

  const int hi4 = (l >> 5) * 4;
#pragma unroll
  for (int fr = 0; fr < 2; ++fr)
#pragma unroll
    for (int fc = 0; fc < 2; ++fc)
#pragma unroll
      for (int r2 = 0; r2 < 16; ++r2) {
        const int c = w * 64 + fr * 32 + (r2 & 3) + 8 * (r2 >> 2) + hi4;
        const int n = n0 + fc * 32 + rl;
        out[((size_t)b * CCH + c) * NPIX + n] = acc[fr][fc][r2];
      }
}

// ---------------- K4 (fallback): direct f32-attn pv (round-1 proven)
__global__ __launch_bounds__(256) void pv_kernel(
    const __bf16* __restrict__ V,    // [B][C][M] bf16
    const float*  __restrict__ attn, // [B][N][M] f32
    float* __restrict__ out)         // [B][C][N]
{
  const int b   = blockIdx.z;
  const int n0  = blockIdx.x * 64;
  const int tid = threadIdx.x;
  const int w = tid >> 6, l = tid & 63;
  const int wr = w >> 1, wc = w & 1;
  const int rl = l & 15, k8 = (l >> 4) * 8;

  const __bf16* vp = V + ((size_t)b * CCH + wr * 128 + rl) * NPIX + k8;
  const float*  ap = attn + ((size_t)b * NPIX + n0 + wc * 32 + rl) * NPIX + k8;

  f32x4 zero = {0.f, 0.f, 0.f, 0.f};
  f32x4 acc[8][2];
#pragma unroll
  for (int fr = 0; fr < 8; ++fr) { acc[fr][0] = zero; acc[fr][1] = zero; }

  for (int ks = 0; ks < 128; ++ks) {
    const int mo = ks * 32;
    bf16x8 a[8];
#pragma unroll
    for (int f = 0; f < 8; ++f)
      a[f] = *reinterpret_cast<const bf16x8*>(vp + (size_t)f * 16 * NPIX + mo);
    bf16x8 bb[2];
#pragma unroll
    for (int f = 0; f < 2; ++f) {
      const float* aq = ap + (size_t)f * 16 * NPIX + mo;
      float4 x = *reinterpret_cast<const float4*>(aq);
      float4 y = *reinterpret_cast<const float4*>(aq + 4);
      bf16x8 t;
      t[0] = (__bf16)x.x; t[1] = (__bf16)x.y; t[2] = (__bf16)x.z; t[3] = (__bf16)x.w;
      t[4] = (__bf16)y.x; t[5] = (__bf16)y.y; t[6] = (__bf16)y.z; t[7] = (__bf16)y.w;
      bb[f] = t;
    }
#pragma unroll
    for (int fr = 0; fr < 8; ++fr) {
      acc[fr][0] = __builtin_amdgcn_mfma_f32_16x16x32_bf16(a[fr], bb[0], acc[fr][0], 0, 0, 0);
      acc[fr][1] = __builtin_amdgcn_mfma_f32_16x16x32_bf16(a[fr], bb[1], acc[fr][1], 0, 0, 0);
    }
  }

  const int cg = (l >> 4) * 4;
#pragma unroll
  for (int fr = 0; fr < 8; ++fr)
#pragma unroll
    for (int fc = 0; fc < 2; ++fc)
#pragma unroll
      for (int r = 0; r < 4; ++r) {
        const int c = wr * 128 + fr * 16 + cg + r;
        const int n = n0 + wc * 32 + fc * 16 + rl;
        out[((size_t)b * CCH + c) * NPIX + n] = acc[fr][fc][r];
      }
}

extern "C" void kernel_launch(void* const* d_in, const int* in_sizes, int n_in,
                              void* d_out, int out_size, void* d_ws, size_t ws_size,
                              hipStream_t stream)
{
  const float* p  = (const float*)d_in[0];
  const float* bi = (const float*)d_in[1];
  const float* Wq = (const float*)d_in[2];
  const float* bq = (const float*)d_in[3];
  const float* Wk = (const float*)d_in[4];
  const float* bk = (const float*)d_in[5];

  float* out  = (float*)d_out;                       // [8][256][4096]
  float* attn = out + (size_t)BATCH * CCH * NPIX;    // [8][4096][4096]

  const size_t QK  = (size_t)BATCH * NPIX * COO;     // 4,194,304 elems
  const size_t VB  = (size_t)BATCH * CCH * NPIX;     // 8,388,608 elems
  const size_t ANB = (size_t)BATCH * NPIX * NPIX;    // 134,217,728 elems
  const size_t need_bf16 = (ANB + 4 * QK + VB) * 2;  // 318,767,104 B

  if (ws_size >= need_bf16) {
    __bf16* attnb = (__bf16*)d_ws;
    __bf16* qhi = attnb + ANB;
    __bf16* qlo = qhi + QK;
    __bf16* khi = qlo + QK;
    __bf16* klo = khi + QK;
    __bf16* Vb  = klo + QK;

    proj3_kernel<<<dim3(16, 4, 8), 256, 0, stream>>>(p,  Wq, bq, qhi, qlo, nullptr);
    proj3_kernel<<<dim3(16, 4, 8), 256, 0, stream>>>(bi, Wk, bk, khi, klo, Vb);
    energy2_kernel<<<8192, 256, 0, stream>>>(qhi, qlo, khi, klo, attn);
    softmax_kernel<true><<<32768, 256, 0, stream>>>(attn, attnb);
    pv3_kernel<<<512, 256, 0, stream>>>(Vb, attnb, out);
  } else {
    __bf16* qhi = (__bf16*)d_ws;
    __bf16* qlo = qhi + QK;
    __bf16* khi = qlo + QK;
    __bf16* klo = khi + QK;
    __bf16* Vb  = klo + QK;

    proj3_kernel<<<dim3(16, 4, 8), 256, 0, stream>>>(p,  Wq, bq, qhi, qlo, nullptr);
    proj3_kernel<<<dim3(16, 4, 8), 256, 0, stream>>>(bi, Wk, bk, khi, klo, Vb);
    energy2_kernel<<<8192, 256, 0, stream>>>(qhi, qlo, khi, klo, attn);
    softmax_kernel<false><<<32768, 256, 0, stream>>>(attn, nullptr);
    pv_kernel<<<dim3(64, 1, 8), 256, 0, stream>>>(Vb, attn, out);
  }
}

// Round 5
// 695.774 us; speedup vs baseline: 1.7324x; 1.1338x over previous
//
#include <hip/hip_runtime.h>
#include <hip/hip_bf16.h>
#include <cstdint>

// SpatialAttention: B=8, C=256, CO=128, H=W=64, N=4096
//   q = Wq@p + bq, k = Wk@b + bk   (proj4: W in LDS; output PACKED in MFMA
//                                   fragment order qf[b][n32][k16][lane][8])
//   e = q k^T  [B,N,N]  split-bf16 3-pass, 32x32x16 MFMA, operand loads are
//                        contiguous 1KB/wave (no LDS needed), XCD swizzle
//   attn = softmax(e)   (output 1; + bf16 linear copy to ws for pv)
//   out = attn @ b^T    (output 0; pv3: 256cx64n, gload_lds 2-phase, swizzle)
//
// d_ws layout (318,767,104 B): attnb bf16[8*4096*4096], qhi/qlo/khi/klo
// 4x bf16[8*4096*128] (fragment-packed), Vb bf16[8*256*4096].

#define BATCH 8
#define CCH   256
#define COO   128
#define NPIX  4096

typedef __bf16 bf16x8 __attribute__((ext_vector_type(8)));
typedef __bf16 bf16x4 __attribute__((ext_vector_type(4)));
typedef float  f32x4  __attribute__((ext_vector_type(4)));
typedef float  f32x16 __attribute__((ext_vector_type(16)));

__device__ __forceinline__ void gload16(const void* g, void* l) {
  __builtin_amdgcn_global_load_lds(
      (const __attribute__((address_space(1))) uint32_t*)g,
      (__attribute__((address_space(3))) uint32_t*)l, 16, 0, 0);
}

// ---------------- K1: proj4 — W tile (32 o-rows) in LDS, 1 pixel/thread.
// Output packed per 32-row x 16-k fragment: f[b][n>>5][o>>4][(n&31)+32*((o>>3)&1)][o&7]
__global__ __launch_bounds__(256) void proj4_kernel(
    const float* __restrict__ X,    // [B][C][N]
    const float* __restrict__ W,    // [CO][C]
    const float* __restrict__ bias, // [CO]
    __bf16* __restrict__ fhi,       // packed [B][128][8][64][8]
    __bf16* __restrict__ flo,
    __bf16* __restrict__ Vb)        // [B][C][N] or nullptr
{
  __shared__ float wlds[32][256];
  __shared__ float blds[32];
  const int b   = blockIdx.z;
  const int o0  = blockIdx.y * 32;
  const int tid = threadIdx.x;
  const int n   = blockIdx.x * 256 + tid;

  for (int i = tid; i < 2048; i += 256) {     // 32 rows x 64 quads
    const int r = i >> 6, q = (i & 63) * 4;
    *reinterpret_cast<float4*>(&wlds[r][q]) =
        *reinterpret_cast<const float4*>(W + (size_t)(o0 + r) * CCH + q);
  }
  if (tid < 32) blds[tid] = bias[o0 + tid];
  __syncthreads();

  const float* Xc = X + (size_t)b * CCH * NPIX + n;
  const bool wV = (Vb != nullptr) && (blockIdx.y == 0);

  float acc[32];
#pragma unroll
  for (int o = 0; o < 32; ++o) acc[o] = 0.f;

  for (int c4 = 0; c4 < CCH; c4 += 4) {
    const float x0 = Xc[(size_t)(c4 + 0) * NPIX];
    const float x1 = Xc[(size_t)(c4 + 1) * NPIX];
    const float x2 = Xc[(size_t)(c4 + 2) * NPIX];
    const float x3 = Xc[(size_t)(c4 + 3) * NPIX];
    if (wV) {
      Vb[((size_t)b * CCH + c4 + 0) * NPIX + n] = (__bf16)x0;
      Vb[((size_t)b * CCH + c4 + 1) * NPIX + n] = (__bf16)x1;
      Vb[((size_t)b * CCH + c4 + 2) * NPIX + n] = (__bf16)x2;
      Vb[((size_t)b * CCH + c4 + 3) * NPIX + n] = (__bf16)x3;
    }
#pragma unroll
    for (int o = 0; o < 32; ++o) {
      const float4 wv = *reinterpret_cast<const float4*>(&wlds[o][c4]);
      acc[o] = fmaf(wv.x, x0, acc[o]);
      acc[o] = fmaf(wv.y, x1, acc[o]);
      acc[o] = fmaf(wv.z, x2, acc[o]);
      acc[o] = fmaf(wv.w, x3, acc[o]);
    }
  }

  const int n32 = n >> 5, nl = n & 31;
#pragma unroll
  for (int g = 0; g < 4; ++g) {
    const int o16 = (o0 >> 4) + (g >> 1);   // k16-block index (0..7)
    const int h   = g & 1;                  // k upper/lower half
    const size_t chunk =
        ((((size_t)b * 128 + n32) * 8 + o16) * 64 + nl + 32 * h) * 8;
    bf16x8 hv, lv;
#pragma unroll
    for (int j = 0; j < 8; ++j) {
      const int o = (g >> 1) * 16 + h * 8 + j;
      const float v = acc[o] + blds[o];
      const __bf16 hh = (__bf16)v;
      hv[j] = hh;
      lv[j] = (__bf16)(v - (float)hh);
    }
    *reinterpret_cast<bf16x8*>(fhi + chunk) = hv;
    *reinterpret_cast<bf16x8*>(flo + chunk) = lv;
  }
}

// ---------------- K2: energy3 — fragment-packed operands, contiguous loads.
__global__ __launch_bounds__(256) void energy3_kernel(
    const __bf16* __restrict__ qh, const __bf16* __restrict__ ql,
    const __bf16* __restrict__ kh, const __bf16* __restrict__ kl,
    float* __restrict__ eout)
{
  const int lin = blockIdx.x;
  const int s   = (lin & 7) * 1024 + (lin >> 3);
  const int b   = s >> 10;
  const int r   = s & 1023;
  const int n0  = (r >> 5) << 7;
  const int m0  = (r & 31) << 7;

  const int tid = threadIdx.x;
  const int w = tid >> 6, l = tid & 63;
  const int wr = w >> 1, wc = w & 1;
  const int rl = l & 31;

  const int qn32 = (n0 >> 5) + wr * 2;  // + fr
  const int km32 = (m0 >> 5) + wc * 2;  // + fc

  // elem offset of fragment (n32, kc) for this lane: (((b*128+n32)*8+kc)*64+l)*8
#define FIDX(n32v, kc) (((((size_t)b * 128 + (n32v)) * 8 + (kc)) * 64 + l) * 8)

  f32x16 acc[2][2];
#pragma unroll
  for (int fr = 0; fr < 2; ++fr)
#pragma unroll
    for (int fc = 0; fc < 2; ++fc)
#pragma unroll
      for (int r2 = 0; r2 < 16; ++r2) acc[fr][fc][r2] = 0.f;

#pragma unroll
  for (int kc = 0; kc < 8; ++kc) {
    bf16x8 ah[2], al[2], bh[2], bl[2];
#pragma unroll
    for (int f = 0; f < 2; ++f) {
      ah[f] = *reinterpret_cast<const bf16x8*>(qh + FIDX(qn32 + f, kc));
      al[f] = *reinterpret_cast<const bf16x8*>(ql + FIDX(qn32 + f, kc));
      bh[f] = *reinterpret_cast<const bf16x8*>(kh + FIDX(km32 + f, kc));
      bl[f] = *reinterpret_cast<const bf16x8*>(kl + FIDX(km32 + f, kc));
    }
#pragma unroll
    for (int fr = 0; fr < 2; ++fr)
#pragma unroll
      for (int fc = 0; fc < 2; ++fc) {
        acc[fr][fc] = __builtin_amdgcn_mfma_f32_32x32x16_bf16(ah[fr], bh[fc], acc[fr][fc], 0, 0, 0);
        acc[fr][fc] = __builtin_amdgcn_mfma_f32_32x32x16_bf16(ah[fr], bl[fc], acc[fr][fc], 0, 0, 0);
        acc[fr][fc] = __builtin_amdgcn_mfma_f32_32x32x16_bf16(al[fr], bh[fc], acc[fr][fc], 0, 0, 0);
      }
  }
#undef FIDX

  const int hi4 = (l >> 5) * 4;
#pragma unroll
  for (int fr = 0; fr < 2; ++fr)
#pragma unroll
    for (int fc = 0; fc < 2; ++fc)
#pragma unroll
      for (int r2 = 0; r2 < 16; ++r2) {
        const int row = n0 + wr * 64 + fr * 32 + (r2 & 3) + 8 * (r2 >> 2) + hi4;
        const int col = m0 + wc * 64 + fc * 32 + rl;
        eout[((size_t)b * NPIX + row) * NPIX + col] = acc[fr][fc][r2];
      }
}

// ---------------- K3: row softmax in place; optional bf16 copy to ws
template <bool WRITE_BF16>
__global__ __launch_bounds__(256) void softmax_kernel(
    float* __restrict__ attn, __bf16* __restrict__ attnb)
{
  const size_t row = blockIdx.x;
  float* p = attn + row * NPIX;
  const int tid = threadIdx.x;
  const int w = tid >> 6, l = tid & 63;

  float4 v[4];
#pragma unroll
  for (int j = 0; j < 4; ++j)
    v[j] = *reinterpret_cast<const float4*>(p + j * 1024 + tid * 4);

  float m = -1e30f;
#pragma unroll
  for (int j = 0; j < 4; ++j)
    m = fmaxf(m, fmaxf(fmaxf(v[j].x, v[j].y), fmaxf(v[j].z, v[j].w)));
#pragma unroll
  for (int off = 32; off; off >>= 1) m = fmaxf(m, __shfl_xor(m, off));

  __shared__ float smax[4];
  __shared__ float ssum[4];
  if (l == 0) smax[w] = m;
  __syncthreads();
  m = fmaxf(fmaxf(smax[0], smax[1]), fmaxf(smax[2], smax[3]));

  float s = 0.f;
#pragma unroll
  for (int j = 0; j < 4; ++j) {
    v[j].x = __expf(v[j].x - m); s += v[j].x;
    v[j].y = __expf(v[j].y - m); s += v[j].y;
    v[j].z = __expf(v[j].z - m); s += v[j].z;
    v[j].w = __expf(v[j].w - m); s += v[j].w;
  }
#pragma unroll
  for (int off = 32; off; off >>= 1) s += __shfl_xor(s, off);
  if (l == 0) ssum[w] = s;
  __syncthreads();
  s = ssum[0] + ssum[1] + ssum[2] + ssum[3];
  const float inv = 1.0f / s;

#pragma unroll
  for (int j = 0; j < 4; ++j) {
    v[j].x *= inv; v[j].y *= inv; v[j].z *= inv; v[j].w *= inv;
    *reinterpret_cast<float4*>(p + j * 1024 + tid * 4) = v[j];
    if (WRITE_BF16) {
      bf16x4 t;
      t[0] = (__bf16)v[j].x; t[1] = (__bf16)v[j].y;
      t[2] = (__bf16)v[j].z; t[3] = (__bf16)v[j].w;
      *reinterpret_cast<bf16x4*>(attnb + row * NPIX + j * 1024 + tid * 4) = t;
    }
  }
}

// ---------------- K4: pv3 — 256c x 64n per WG, attn read once, 32x32x16,
// gload_lds 2-phase with XOR-swizzled LDS. LDS 80KB -> 2 WG/CU.
__global__ __launch_bounds__(256) void pv3_kernel(
    const __bf16* __restrict__ V,   // [B][C][M] bf16
    const __bf16* __restrict__ An,  // [B][N][M] bf16 (softmaxed)
    float* __restrict__ out)        // [B][C][N]
{
  __shared__ uint8_t ldsb[2 * 40960];
  const int lin = blockIdx.x;                 // 512 blocks
  const int s   = (lin & 7) * 64 + (lin >> 3);
  const int n0  = (s & 63) * 64;
  const int b   = s >> 6;
  const int tid = threadIdx.x;
  const int w = tid >> 6, l = tid & 63;
  const int rl = l & 31;

  const uint8_t* Vbase = (const uint8_t*)(V + (size_t)b * CCH * NPIX);
  const uint8_t* Abase = (const uint8_t*)(An + ((size_t)b * NPIX + n0) * NPIX);

  f32x16 acc[2][2];
#pragma unroll
  for (int fr = 0; fr < 2; ++fr)
#pragma unroll
    for (int fc = 0; fc < 2; ++fc)
#pragma unroll
      for (int r2 = 0; r2 < 16; ++r2) acc[fr][fc][r2] = 0.f;

#define STAGE(buf, t)                                                         \
  {                                                                           \
    const int tb = (t) * 128;                                                 \
    _Pragma("unroll")                                                         \
    for (int q = 0; q < 8; ++q) {                                             \
      const int dst = q * 4096 + tid * 16;                                    \
      const int row = dst >> 7, colb = dst & 127;                             \
      gload16(Vbase + (size_t)row * 8192 + tb + (colb ^ ((row & 7) << 4)),    \
              ldsb + (buf) * 40960 + dst);                                    \
    }                                                                         \
    _Pragma("unroll")                                                         \
    for (int q = 0; q < 2; ++q) {                                             \
      const int dst = q * 4096 + tid * 16;                                    \
      const int row = dst >> 7, colb = dst & 127;                             \
      gload16(Abase + (size_t)row * 8192 + tb + (colb ^ ((row & 7) << 4)),    \
              ldsb + (buf) * 40960 + 32768 + dst);                            \
    }                                                                         \
  }

  STAGE(0, 0);
  __syncthreads();

  for (int t = 0; t < 64; ++t) {
    const int cur = t & 1;
    if (t + 1 < 64) STAGE(cur ^ 1, t + 1);
    const uint8_t* Vt = ldsb + cur * 40960;
    const uint8_t* At = Vt + 32768;
#pragma unroll
    for (int kc = 0; kc < 4; ++kc) {
      const int colb = kc * 32 + ((l >> 5) << 4);
      bf16x8 a[2], bb[2];
#pragma unroll
      for (int f = 0; f < 2; ++f) {
        const int row = w * 64 + f * 32 + rl;
        a[f] = *reinterpret_cast<const bf16x8*>(
            Vt + row * 128 + (colb ^ ((row & 7) << 4)));
      }
#pragma unroll
      for (int f = 0; f < 2; ++f) {
        const int row = f * 32 + rl;
        bb[f] = *reinterpret_cast<const bf16x8*>(
            At + row * 128 + (colb ^ ((row & 7) << 4)));
      }
#pragma unroll
      for (int fr = 0; fr < 2; ++fr)
#pragma unroll
        for (int fc = 0; fc < 2; ++fc)
          acc[fr][fc] = __builtin_amdgcn_mfma_f32_32x32x16_bf16(a[fr], bb[fc], acc[fr][fc], 0, 0, 0);
    }
    __syncthreads();
  }
#undef STAGE

  const int hi4 = (l >> 5) * 4;
#pragma unroll
  for (int fr = 0; fr < 2; ++fr)
#pragma unroll
    for (int fc = 0; fc < 2; ++fc)
#pragma unroll
      for (int r2 = 0; r2 < 16; ++r2) {
        const int c = w * 64 + fr * 32 + (r2 & 3) + 8 * (r2 >> 2) + hi4;
        const int n = n0 + fc * 32 + rl;
        out[((size_t)b * CCH + c) * NPIX + n] = acc[fr][fc][r2];
      }
}

// ---------------- K4 (fallback): direct f32-attn pv
__global__ __launch_bounds__(256) void pv_kernel(
    const __bf16* __restrict__ V,    // [B][C][M] bf16
    const float*  __restrict__ attn, // [B][N][M] f32
    float* __restrict__ out)         // [B][C][N]
{
  const int b   = blockIdx.z;
  const int n0  = blockIdx.x * 64;
  const int tid = threadIdx.x;
  const int w = tid >> 6, l = tid & 63;
  const int wr = w >> 1, wc = w & 1;
  const int rl = l & 15, k8 = (l >> 4) * 8;

  const __bf16* vp = V + ((size_t)b * CCH + wr * 128 + rl) * NPIX + k8;
  const float*  ap = attn + ((size_t)b * NPIX + n0 + wc * 32 + rl) * NPIX + k8;

  f32x4 zero = {0.f, 0.f, 0.f, 0.f};
  f32x4 acc[8][2];
#pragma unroll
  for (int fr = 0; fr < 8; ++fr) { acc[fr][0] = zero; acc[fr][1] = zero; }

  for (int ks = 0; ks < 128; ++ks) {
    const int mo = ks * 32;
    bf16x8 a[8];
#pragma unroll
    for (int f = 0; f < 8; ++f)
      a[f] = *reinterpret_cast<const bf16x8*>(vp + (size_t)f * 16 * NPIX + mo);
    bf16x8 bb[2];
#pragma unroll
    for (int f = 0; f < 2; ++f) {
      const float* aq = ap + (size_t)f * 16 * NPIX + mo;
      float4 x = *reinterpret_cast<const float4*>(aq);
      float4 y = *reinterpret_cast<const float4*>(aq + 4);
      bf16x8 t;
      t[0] = (__bf16)x.x; t[1] = (__bf16)x.y; t[2] = (__bf16)x.z; t[3] = (__bf16)x.w;
      t[4] = (__bf16)y.x; t[5] = (__bf16)y.y; t[6] = (__bf16)y.z; t[7] = (__bf16)y.w;
      bb[f] = t;
    }
#pragma unroll
    for (int fr = 0; fr < 8; ++fr) {
      acc[fr][0] = __builtin_amdgcn_mfma_f32_16x16x32_bf16(a[fr], bb[0], acc[fr][0], 0, 0, 0);
      acc[fr][1] = __builtin_amdgcn_mfma_f32_16x16x32_bf16(a[fr], bb[1], acc[fr][1], 0, 0, 0);
    }
  }

  const int cg = (l >> 4) * 4;
#pragma unroll
  for (int fr = 0; fr < 8; ++fr)
#pragma unroll
    for (int fc = 0; fc < 2; ++fc)
#pragma unroll
      for (int r = 0; r < 4; ++r) {
        const int c = wr * 128 + fr * 16 + cg + r;
        const int n = n0 + wc * 32 + fc * 16 + rl;
        out[((size_t)b * CCH + c) * NPIX + n] = acc[fr][fc][r];
      }
}

extern "C" void kernel_launch(void* const* d_in, const int* in_sizes, int n_in,
                              void* d_out, int out_size, void* d_ws, size_t ws_size,
                              hipStream_t stream)
{
  const float* p  = (const float*)d_in[0];
  const float* bi = (const float*)d_in[1];
  const float* Wq = (const float*)d_in[2];
  const float* bq = (const float*)d_in[3];
  const float* Wk = (const float*)d_in[4];
  const float* bk = (const float*)d_in[5];

  float* out  = (float*)d_out;                       // [8][256][4096]
  float* attn = out + (size_t)BATCH * CCH * NPIX;    // [8][4096][4096]

  const size_t QK  = (size_t)BATCH * NPIX * COO;     // 4,194,304 elems
  const size_t VB  = (size_t)BATCH * CCH * NPIX;     // 8,388,608 elems
  const size_t ANB = (size_t)BATCH * NPIX * NPIX;    // 134,217,728 elems
  const size_t need_bf16 = (ANB + 4 * QK + VB) * 2;  // 318,767,104 B

  if (ws_size >= need_bf16) {
    __bf16* attnb = (__bf16*)d_ws;
    __bf16* qhi = attnb + ANB;
    __bf16* qlo = qhi + QK;
    __bf16* khi = qlo + QK;
    __bf16* klo = khi + QK;
    __bf16* Vb  = klo + QK;

    proj4_kernel<<<dim3(16, 4, 8), 256, 0, stream>>>(p,  Wq, bq, qhi, qlo, nullptr);
    proj4_kernel<<<dim3(16, 4, 8), 256, 0, stream>>>(bi, Wk, bk, khi, klo, Vb);
    energy3_kernel<<<8192, 256, 0, stream>>>(qhi, qlo, khi, klo, attn);
    softmax_kernel<true><<<32768, 256, 0, stream>>>(attn, attnb);
    pv3_kernel<<<512, 256, 0, stream>>>(Vb, attnb, out);
  } else {
    __bf16* qhi = (__bf16*)d_ws;
    __bf16* qlo = qhi + QK;
    __bf16* khi = qlo + QK;
    __bf16* klo = khi + QK;
    __bf16* Vb  = klo + QK;

    proj4_kernel<<<dim3(16, 4, 8), 256, 0, stream>>>(p,  Wq, bq, qhi, qlo, nullptr);
    proj4_kernel<<<dim3(16, 4, 8), 256, 0, stream>>>(bi, Wk, bk, khi, klo, Vb);
    energy3_kernel<<<8192, 256, 0, stream>>>(qhi, qlo, khi, klo, attn);
    softmax_kernel<false><<<32768, 256, 0, stream>>>(attn, nullptr);
    pv_kernel<<<dim3(64, 1, 8), 256, 0, stream>>>(Vb, attn, out);
  }
}